// Round 5
// baseline (256.241 us; speedup 1.0000x reference)
//
#include <hip/hip_runtime.h>

#define CDIM 512
#define NH 8
#define HWDIM 4096

typedef float f32x2 __attribute__((ext_vector_type(2)));
typedef float f32x4 __attribute__((ext_vector_type(4)));

// Workspace layout (floats): wvT[4096] | wp[4096] | Sp[8*16*8*4096] | S[16*8*4096]
#define WS_WVT 0
#define WS_WP 4096
#define WS_SP 8192
#define WS_S (8192 + 8 * 16 * NH * HWDIM)
#define WS_NEEDED_BYTES ((size_t)(8192 + 8 * 16 * NH * HWDIM + 16 * NH * HWDIM) * 4)

// Fold weights: wvT[c*8+n] = sum_j wqkv[(1024+64n+j)*512 + c]
//               wp [o*8+n] = sum_j wproj[o*512 + 64n + j]
__global__ __launch_bounds__(256) void prep_kernel(
    const float* __restrict__ wqkv, const float* __restrict__ wproj,
    float* __restrict__ wvT, float* __restrict__ wp) {
  int idx = blockIdx.x * 256 + threadIdx.x;
  if (idx < 4096) {
    int c = idx >> 3, n = idx & 7;
    const float* p = wqkv + (size_t)(1024 + n * 64) * CDIM + c;
    float s = 0.f;
#pragma unroll 8
    for (int j = 0; j < 64; ++j) s += p[(size_t)j * CDIM];
    wvT[idx] = s;
  } else if (idx < 8192) {
    int i2 = idx - 4096;
    int o = i2 >> 3, n = i2 & 7;
    const float* p = wproj + (size_t)o * CDIM + n * 64;
    float s = 0.f;
#pragma unroll 8
    for (int j = 0; j < 64; ++j) s += p[j];
    wp[i2] = s;
  }
}

// ---------------- contiguous-stream path ----------------

// sA: partial S. Block = (b, chunk k of 64 channels, half h of hw).
// Block reads 64 half-rows of 8 KB each, CONTIGUOUS per half-row, consecutive
// channels -> near-sequential 512 KB sweep per block (DRAM row-hit friendly).
// Thread owns 4 spatial positions; acc[8 heads][4 pos] in regs.
// Sp[k][b][n][hw] = sum_{c in chunk k} wvT[c,n] * x[b,c,hw]
__global__ __launch_bounds__(512) void sA_kernel(
    const float* __restrict__ x, const float* __restrict__ wvT,
    float* __restrict__ Sp) {
  __shared__ float sWv[512];   // 64 ch x 8 heads

  const int t = threadIdx.x;
  const int bid = blockIdx.x;          // 256 blocks: b(16) x k(8) x h(2)
  const int b = bid >> 4;
  const int k = (bid >> 1) & 7;
  const int h = bid & 1;
  const int c0 = k * 64;

  sWv[t] = wvT[c0 * 8 + t];
  __syncthreads();

  const int pos = h * 2048 + t * 4;
  const float* xb = x + ((size_t)(b * CDIM + c0)) * HWDIM + pos;

  float acc[NH][4];
#pragma unroll
  for (int n = 0; n < NH; ++n) { acc[n][0] = acc[n][1] = acc[n][2] = acc[n][3] = 0.f; }

  for (int g = 0; g < 8; ++g) {
    float4 xv[8];
#pragma unroll
    for (int j = 0; j < 8; ++j)
      xv[j] = *(const float4*)(xb + (size_t)(g * 8 + j) * HWDIM);
#pragma unroll
    for (int j = 0; j < 8; ++j) {
      const int c = g * 8 + j;
      const float4 w0 = *(const float4*)&sWv[c * 8];
      const float4 w1 = *(const float4*)&sWv[c * 8 + 4];
      const float wn[8] = {w0.x, w0.y, w0.z, w0.w, w1.x, w1.y, w1.z, w1.w};
      const float xr[4] = {xv[j].x, xv[j].y, xv[j].z, xv[j].w};
#pragma unroll
      for (int n = 0; n < NH; ++n) {
#pragma unroll
        for (int p = 0; p < 4; ++p) acc[n][p] = fmaf(wn[n], xr[p], acc[n][p]);
      }
    }
  }

  float* sp = Sp + ((size_t)(k * 16 + b) * NH) * HWDIM + pos;
#pragma unroll
  for (int n = 0; n < NH; ++n)
    *(float4*)(sp + (size_t)n * HWDIM) = make_float4(acc[n][0], acc[n][1], acc[n][2], acc[n][3]);
}

// sR: S = sum_k Sp[k]. 32 MB reads (LLC-hot) + 2 MB writes.
__global__ __launch_bounds__(512) void sR_kernel(
    const float* __restrict__ Sp, float* __restrict__ S) {
  const size_t fid = (size_t)blockIdx.x * 512 + threadIdx.x;  // 131072 float4s
  const size_t base = fid * 4;
  float4 s = make_float4(0.f, 0.f, 0.f, 0.f);
#pragma unroll
  for (int k = 0; k < 8; ++k) {
    const float4 a = *(const float4*)(Sp + base + (size_t)k * 16 * NH * HWDIM);
    s.x += a.x; s.y += a.y; s.z += a.z; s.w += a.w;
  }
  *(float4*)(S + base) = s;
}

// yK: y[b,o,hw] = bias[o] + sum_n wp[o,n]*S[b,n,hw]. Pure write-stream, nt stores.
__global__ __launch_bounds__(256) void yK_kernel(
    const float* __restrict__ S, const float* __restrict__ wp,
    const float* __restrict__ bias, float* __restrict__ y) {
  __shared__ float sWp[4096];
  __shared__ float sB[512];

  const int t = threadIdx.x;
  for (int i = t; i < 4096; i += 256) sWp[i] = wp[i];
  for (int i = t; i < 512; i += 256) sB[i] = bias[i];
  __syncthreads();

  const int bid = blockIdx.x;       // 512: b(16) x span(4) x og(8)
  const int b = bid >> 5;
  const int span = (bid >> 3) & 3;
  const int og = bid & 7;
  const int hwo = span * 1024 + t * 4;

  float s[NH][4];
#pragma unroll
  for (int n = 0; n < NH; ++n) {
    const float4 a = *(const float4*)&S[((size_t)b * NH + n) * HWDIM + hwo];
    s[n][0] = a.x; s[n][1] = a.y; s[n][2] = a.z; s[n][3] = a.w;
  }

  float* yb = y + ((size_t)b * CDIM) * HWDIM + hwo;
  const int o0 = og * 64;
#pragma unroll 4
  for (int oo = 0; oo < 64; ++oo) {
    const int o = o0 + oo;
    const float4 w0 = *(const float4*)&sWp[o * 8];
    const float4 w1 = *(const float4*)&sWp[o * 8 + 4];
    const float wn[8] = {w0.x, w0.y, w0.z, w0.w, w1.x, w1.y, w1.z, w1.w};
    const float bb = sB[o];
    f32x4 r;
    r.x = bb; r.y = bb; r.z = bb; r.w = bb;
#pragma unroll
    for (int n = 0; n < NH; ++n) {
      r.x = fmaf(wn[n], s[n][0], r.x);
      r.y = fmaf(wn[n], s[n][1], r.y);
      r.z = fmaf(wn[n], s[n][2], r.z);
      r.w = fmaf(wn[n], s[n][3], r.w);
    }
    __builtin_nontemporal_store(r, (f32x4*)(yb + (size_t)o * HWDIM));
  }
}

// ---------------- fallback fused path (R4, 81 us) ----------------
#define TILE 128
#define NT 512
__global__ __launch_bounds__(NT, 4) void fused_kernel(
    const float* __restrict__ x, const float* __restrict__ bias,
    const float* __restrict__ wvT, const float* __restrict__ wp,
    float* __restrict__ y) {
  __shared__ __align__(16) float sWv[4096];
  __shared__ __align__(16) float sWp[4096];
  __shared__ __align__(16) float sB[512];
  __shared__ __align__(16) float sS[8][NH][TILE];

  const int t = threadIdx.x;
  for (int i = t; i < 4096; i += NT) { sWv[i] = wvT[i]; sWp[i] = wp[i]; }
  if (t < 512) sB[t] = bias[t];
  __syncthreads();

  const int wave = t >> 6;
  const int lane = t & 63;
  const int pos0 = blockIdx.x * TILE;
  const int b = pos0 >> 12;
  const int hw0 = pos0 & (HWDIM - 1);
  const float* xb = x + ((size_t)b * CDIM) * HWDIM + hw0 + lane * 2;

  float acc[NH][2];
#pragma unroll
  for (int n = 0; n < NH; ++n) { acc[n][0] = 0.f; acc[n][1] = 0.f; }

  const int c0 = wave * 64;
#pragma unroll 8
  for (int cc = 0; cc < 64; ++cc) {
    const int c = c0 + cc;
    const float2 xv = *(const float2*)(xb + (size_t)c * HWDIM);
    const float4 w0 = *(const float4*)&sWv[c * 8];
    const float4 w1 = *(const float4*)&sWv[c * 8 + 4];
    const float wn[8] = {w0.x, w0.y, w0.z, w0.w, w1.x, w1.y, w1.z, w1.w};
#pragma unroll
    for (int n = 0; n < NH; ++n) {
      acc[n][0] = fmaf(wn[n], xv.x, acc[n][0]);
      acc[n][1] = fmaf(wn[n], xv.y, acc[n][1]);
    }
  }
#pragma unroll
  for (int n = 0; n < NH; ++n)
    *(float2*)&sS[wave][n][lane * 2] = make_float2(acc[n][0], acc[n][1]);
  __syncthreads();

  float S2[NH][2];
#pragma unroll
  for (int n = 0; n < NH; ++n) {
    float s0 = 0.f, s1 = 0.f;
#pragma unroll
    for (int w = 0; w < 8; ++w) {
      const float2 a = *(const float2*)&sS[w][n][lane * 2];
      s0 += a.x; s1 += a.y;
    }
    S2[n][0] = s0; S2[n][1] = s1;
  }

  float* yb = y + ((size_t)b * CDIM) * HWDIM + hw0 + lane * 2;
  const int o0 = wave * 64;
#pragma unroll 4
  for (int oo = 0; oo < 64; ++oo) {
    const int o = o0 + oo;
    const float4 w0 = *(const float4*)&sWp[o * 8];
    const float4 w1 = *(const float4*)&sWp[o * 8 + 4];
    const float wn[8] = {w0.x, w0.y, w0.z, w0.w, w1.x, w1.y, w1.z, w1.w};
    const float bb = sB[o];
    float r0 = bb, r1 = bb;
#pragma unroll
    for (int n = 0; n < NH; ++n) {
      r0 = fmaf(wn[n], S2[n][0], r0);
      r1 = fmaf(wn[n], S2[n][1], r1);
    }
    f32x2 out;
    out.x = r0; out.y = r1;
    __builtin_nontemporal_store(out, (f32x2*)(yb + (size_t)o * HWDIM));
  }
}

extern "C" void kernel_launch(void* const* d_in, const int* in_sizes, int n_in,
                              void* d_out, int out_size, void* d_ws, size_t ws_size,
                              hipStream_t stream) {
  const float* x     = (const float*)d_in[0];
  const float* wqkv  = (const float*)d_in[1];
  const float* wproj = (const float*)d_in[2];
  const float* bproj = (const float*)d_in[3];
  float* y = (float*)d_out;

  float* wvT = (float*)d_ws + WS_WVT;
  float* wp  = (float*)d_ws + WS_WP;

  prep_kernel<<<32, 256, 0, stream>>>(wqkv, wproj, wvT, wp);

  if (ws_size >= WS_NEEDED_BYTES) {
    float* Sp = (float*)d_ws + WS_SP;
    float* S  = (float*)d_ws + WS_S;
    sA_kernel<<<256, 512, 0, stream>>>(x, wvT, Sp);
    sR_kernel<<<256, 512, 0, stream>>>(Sp, S);
    yK_kernel<<<512, 256, 0, stream>>>(S, wp, bproj, y);
  } else {
    fused_kernel<<<HWDIM * 16 / TILE, NT, 0, stream>>>(x, bproj, wvT, wp, y);
  }
}

// Round 6
// 247.630 us; speedup vs baseline: 1.0348x; 1.0348x over previous
//
#include <hip/hip_runtime.h>

#define CDIM 512
#define NH 8
#define HWDIM 4096
#define TILE 128   // spatial positions per block
#define NT 512     // threads per block = 8 waves

typedef float f32x2 __attribute__((ext_vector_type(2)));

// Fold weights: wvT[c*8+n] = sum_j wqkv[(1024+64n+j)*512 + c]
//               wp [o*8+n] = sum_j wproj[o*512 + 64n + j]
__global__ __launch_bounds__(256) void prep_kernel(
    const float* __restrict__ wqkv, const float* __restrict__ wproj,
    float* __restrict__ wvT, float* __restrict__ wp) {
  int idx = blockIdx.x * 256 + threadIdx.x;
  if (idx < 4096) {
    int c = idx >> 3, n = idx & 7;
    const float* p = wqkv + (size_t)(1024 + n * 64) * CDIM + c;
    float s = 0.f;
#pragma unroll 8
    for (int j = 0; j < 64; ++j) s += p[(size_t)j * CDIM];
    wvT[idx] = s;
  } else if (idx < 8192) {
    int i2 = idx - 4096;
    int o = i2 >> 3, n = i2 & 7;
    const float* p = wproj + (size_t)o * CDIM + n * 64;
    float s = 0.f;
#pragma unroll 8
    for (int j = 0; j < 64; ++j) s += p[j];
    wp[i2] = s;
  }
}

// y[b,o,s] = bias[o] + sum_n wp[o,n] * (sum_c wvT[c,n] * x[b,c,s])
// 8 waves: phase 1 splits 512 channels 64/wave; phase 2 splits 512 outputs 64/wave.
// CHANNEL-PHASE STAGGER: every block starts its channel sweep (and output sweep)
// at a block-dependent rotation. Without it, all blocks touch the same
// 16KB-strided row at the same instant -> instantaneous address set aliases to a
// few HBM channels -> ~2.4 TB/s wall (seen in R0/R1/R2/R5 regardless of shape).
// Rotation keeps per-block sequential locality + wave coalescing, but spreads
// the device-wide active set over all 512 rows -> all channels busy.
__global__ __launch_bounds__(NT, 4) void fused_kernel(
    const float* __restrict__ x, const float* __restrict__ bias,
    const float* __restrict__ wvT, const float* __restrict__ wp,
    float* __restrict__ y) {
  __shared__ __align__(16) float sWv[4096];            // [c][n]
  __shared__ __align__(16) float sWp[4096];            // [o][n]
  __shared__ __align__(16) float sB[512];
  __shared__ __align__(16) float sS[8][NH][TILE];      // per-wave partial S (32 KB)

  const int t = threadIdx.x;
  for (int i = t; i < 4096; i += NT) { sWv[i] = wvT[i]; sWp[i] = wp[i]; }
  if (t < 512) sB[t] = bias[t];
  __syncthreads();

  const int wave = t >> 6;
  const int lane = t & 63;
  const int pos0 = blockIdx.x * TILE;        // 128 | 4096 so blocks never straddle b
  const int b = pos0 >> 12;
  const int hw0 = pos0 & (HWDIM - 1);
  const float* xb = x + ((size_t)b * CDIM) * HWDIM + hw0 + lane * 2;

  const int rot  = (blockIdx.x * 37) & 63;   // read-phase stagger
  const int rot2 = (blockIdx.x * 23) & 63;   // write-phase stagger

  // ---- phase 1: S[n, pos] partials; wave handles 64 channels ----
  float acc[NH][2];
#pragma unroll
  for (int n = 0; n < NH; ++n) { acc[n][0] = 0.f; acc[n][1] = 0.f; }

  const int c0 = wave * 64;
#pragma unroll 8
  for (int cc = 0; cc < 64; ++cc) {
    const int c = c0 + ((cc + rot) & 63);
    const float2 xv = *(const float2*)(xb + (size_t)c * HWDIM);
    const float4 w0 = *(const float4*)&sWv[c * 8];
    const float4 w1 = *(const float4*)&sWv[c * 8 + 4];
    const float wn[8] = {w0.x, w0.y, w0.z, w0.w, w1.x, w1.y, w1.z, w1.w};
#pragma unroll
    for (int n = 0; n < NH; ++n) {
      acc[n][0] = fmaf(wn[n], xv.x, acc[n][0]);
      acc[n][1] = fmaf(wn[n], xv.y, acc[n][1]);
    }
  }

#pragma unroll
  for (int n = 0; n < NH; ++n) {
    *(float2*)&sS[wave][n][lane * 2] = make_float2(acc[n][0], acc[n][1]);
  }
  __syncthreads();

  // ---- phase 2: reduce S across 8 waves, expand to 512 outputs ----
  float S2[NH][2];
#pragma unroll
  for (int n = 0; n < NH; ++n) {
    float s0 = 0.f, s1 = 0.f;
#pragma unroll
    for (int w = 0; w < 8; ++w) {
      const float2 a = *(const float2*)&sS[w][n][lane * 2];
      s0 += a.x; s1 += a.y;
    }
    S2[n][0] = s0; S2[n][1] = s1;
  }

  float* yb = y + ((size_t)b * CDIM) * HWDIM + hw0 + lane * 2;
  const int o0 = wave * 64;
#pragma unroll 4
  for (int oo = 0; oo < 64; ++oo) {
    const int o = o0 + ((oo + rot2) & 63);
    const float4 w0 = *(const float4*)&sWp[o * 8];
    const float4 w1 = *(const float4*)&sWp[o * 8 + 4];
    const float wn[8] = {w0.x, w0.y, w0.z, w0.w, w1.x, w1.y, w1.z, w1.w};
    const float bb = sB[o];
    float r0 = bb, r1 = bb;
#pragma unroll
    for (int n = 0; n < NH; ++n) {
      r0 = fmaf(wn[n], S2[n][0], r0);
      r1 = fmaf(wn[n], S2[n][1], r1);
    }
    f32x2 out;
    out.x = r0; out.y = r1;
    __builtin_nontemporal_store(out, (f32x2*)(yb + (size_t)o * HWDIM));
  }
}

extern "C" void kernel_launch(void* const* d_in, const int* in_sizes, int n_in,
                              void* d_out, int out_size, void* d_ws, size_t ws_size,
                              hipStream_t stream) {
  const float* x     = (const float*)d_in[0];
  const float* wqkv  = (const float*)d_in[1];
  const float* wproj = (const float*)d_in[2];
  const float* bproj = (const float*)d_in[3];
  float* y = (float*)d_out;

  float* wvT = (float*)d_ws;        // 4096 floats
  float* wp  = wvT + 4096;          // 4096 floats (32 KB total scratch)

  prep_kernel<<<32, 256, 0, stream>>>(wqkv, wproj, wvT, wp);
  fused_kernel<<<HWDIM * 16 / TILE, NT, 0, stream>>>(x, bproj, wvT, wp, y);
}